// Round 1
// baseline (1580.625 us; speedup 1.0000x reference)
//
#include <hip/hip_runtime.h>
#include <hip/hip_bf16.h>

#define BATCH 2048
#define DIM   2048
#define KR    49     // K_REG (= L, number of V slots)
#define KC    64     // K-chunk of D per MFMA staging step
#define LSTR  72     // LDS row stride in bf16 elems (64 + 8 pad)

typedef __attribute__((ext_vector_type(8))) short short8;   // 8 bf16 = 4 VGPRs
typedef __attribute__((ext_vector_type(4))) float float4v;  // MFMA accumulator

__device__ __forceinline__ unsigned short f2b(float x) {
    __hip_bfloat16 h = __float2bfloat16(x);
    return __builtin_bit_cast(unsigned short, h);
}

// Kernel 1: W_gt[b,k] = h_t[b]·W_g[k];  Ts[b,k] = tanh(s_t[b]·W_s[k] + W_gt)·w_h_s[k];
// plus fp32->bf16 conversion of W_v (49*2048 == 2048*49, so one elem per thread).
__global__ __launch_bounds__(256) void precompute_kernel(
    const float* __restrict__ h_t, const float* __restrict__ s_t,
    const float* __restrict__ W_v, const float* __restrict__ W_g,
    const float* __restrict__ W_s, const float* __restrict__ w_h_s,
    float* __restrict__ Wgt, float* __restrict__ Ts,
    unsigned short* __restrict__ Wvb)
{
    const int idx = blockIdx.x * 256 + threadIdx.x;
    if (idx >= BATCH * KR) return;
    Wvb[idx] = f2b(W_v[idx]);          // exact 1:1 cover of 49*2048 elements
    const int b = idx / KR;
    const int k = idx - b * KR;
    const float4* h4 = (const float4*)(h_t + (size_t)b * DIM);
    const float4* s4 = (const float4*)(s_t + (size_t)b * DIM);
    const float4* g4 = (const float4*)(W_g + (size_t)k * DIM);
    const float4* w4 = (const float4*)(W_s + (size_t)k * DIM);
    float ag = 0.f, as = 0.f;
    #pragma unroll 4
    for (int d = 0; d < DIM / 4; ++d) {
        float4 hv = h4[d], gv = g4[d];
        ag += hv.x * gv.x + hv.y * gv.y + hv.z * gv.z + hv.w * gv.w;
        float4 sv = s4[d], wv = w4[d];
        as += sv.x * wv.x + sv.y * wv.y + sv.z * wv.z + sv.w * wv.w;
    }
    Wgt[idx] = ag;
    Ts[idx]  = tanhf(as + ag) * w_h_s[k];
}

// Kernel 2: one block per batch b. Pass 1: T = V[b](49x2048) · W_v^T via bf16 MFMA,
// z_l = sum_k tanh(T+Wgt)·w_h. Softmax over [z_0..z_48, sent]. Pass 2: out.
__global__ __launch_bounds__(256) void fused_kernel(
    const float* __restrict__ V, const float* __restrict__ h_t,
    const float* __restrict__ s_t, const float* __restrict__ w_h,
    const float* __restrict__ Wgt, const float* __restrict__ Ts,
    const unsigned short* __restrict__ Wvb, float* __restrict__ out)
{
    const int b    = blockIdx.x;
    const int tid  = threadIdx.x;
    const int wave = tid >> 6;
    const int lane = tid & 63;
    const int quad = lane >> 4;
    const int l16  = lane & 15;

    __shared__ unsigned short Av[64 * LSTR];  // V tile, rows = l (padded to 64)
    __shared__ unsigned short Bw[64 * LSTR];  // W_v tile, rows = k (padded to 64)
    __shared__ float z_lds[64];
    __shared__ float alpha_l[KR];
    __shared__ float wgt_l[KR];
    __shared__ float wh_l[KR];
    __shared__ float beta_sh;

    if (tid < KR) {
        wgt_l[tid] = Wgt[(size_t)b * KR + tid];
        wh_l[tid]  = w_h[tid];
    }
    // zero pad rows 49..63 once (they persist across chunks)
    for (int i = tid; i < 15 * LSTR; i += 256) {
        Av[49 * LSTR + i] = 0;
        Bw[49 * LSTR + i] = 0;
    }

    float4v acc[4];
    #pragma unroll
    for (int t = 0; t < 4; ++t) acc[t] = (float4v){0.f, 0.f, 0.f, 0.f};

    const float* Vb = V + (size_t)b * KR * DIM;

    for (int kc = 0; kc < DIM; kc += KC) {
        // stage: 49 rows x 64 cols of V (fp32->bf16) and of Wvb (bf16), as float4/ushort4
        for (int e = tid; e < KR * (KC / 4); e += 256) {  // 784 float4 groups
            const int row = e >> 4;     // KC/4 = 16 groups per row
            const int c4  = e & 15;
            float4 v = *(const float4*)(Vb + (size_t)row * DIM + kc + c4 * 4);
            ushort4 pv;
            pv.x = f2b(v.x); pv.y = f2b(v.y); pv.z = f2b(v.z); pv.w = f2b(v.w);
            *(ushort4*)&Av[row * LSTR + c4 * 4] = pv;
            ushort4 wv = *(const ushort4*)(Wvb + (size_t)row * DIM + kc + c4 * 4);
            *(ushort4*)&Bw[row * LSTR + c4 * 4] = wv;
        }
        __syncthreads();
        // MFMA: wave w owns output rows 16w..16w+15, all 4 col-tiles
        const unsigned short* ap = &Av[(wave * 16 + l16) * LSTR + quad * 8];
        #pragma unroll
        for (int s = 0; s < 2; ++s) {          // two k-steps of 32 within the 64-chunk
            short8 af = *(const short8*)(ap + s * 32);
            #pragma unroll
            for (int t = 0; t < 4; ++t) {
                short8 bf = *(const short8*)(&Bw[(t * 16 + l16) * LSTR + quad * 8 + s * 32]);
                acc[t] = __builtin_amdgcn_mfma_f32_16x16x32_bf16(af, bf, acc[t], 0, 0, 0);
            }
        }
        __syncthreads();
    }

    // z_l = sum_k tanh(T[l,k] + Wgt[k]) * w_h[k]
    // lane holds C[row = wave*16 + quad*4 + r][col = t*16 + l16]
    float zp[4] = {0.f, 0.f, 0.f, 0.f};
    #pragma unroll
    for (int t = 0; t < 4; ++t) {
        const int col = t * 16 + l16;
        if (col < KR) {
            const float wg = wgt_l[col];
            const float wh = wh_l[col];
            #pragma unroll
            for (int r = 0; r < 4; ++r)
                zp[r] += tanhf(acc[t][r] + wg) * wh;
        }
    }
    #pragma unroll
    for (int off = 1; off < 16; off <<= 1) {
        #pragma unroll
        for (int r = 0; r < 4; ++r)
            zp[r] += __shfl_xor(zp[r], off, 64);
    }
    if (l16 == 0) {
        #pragma unroll
        for (int r = 0; r < 4; ++r) {
            const int row = wave * 16 + quad * 4 + r;
            if (row < KR) z_lds[row] = zp[r];
        }
    }
    __syncthreads();

    // softmax over 50 logits in wave 0; sent = sum_k Ts[b,k]
    if (wave == 0) {
        float tv = (lane < KR) ? Ts[(size_t)b * KR + lane] : 0.f;
        float sent = tv;
        #pragma unroll
        for (int off = 1; off < 64; off <<= 1) sent += __shfl_xor(sent, off, 64);
        float x = (lane < KR) ? z_lds[lane] : ((lane == KR) ? sent : -1e30f);
        float m = x;
        #pragma unroll
        for (int off = 1; off < 64; off <<= 1) m = fmaxf(m, __shfl_xor(m, off, 64));
        float e = (lane <= KR) ? expf(x - m) : 0.f;
        float s = e;
        #pragma unroll
        for (int off = 1; off < 64; off <<= 1) s += __shfl_xor(s, off, 64);
        const float a = e / s;
        if (lane < KR) alpha_l[lane] = a;
        if (lane == KR) beta_sh = a;
    }
    __syncthreads();

    // pass 2: out[b,d] = beta*s_t + (1-beta)*sum_l alpha_l V[b,l,d] + h_t
    const float bta = beta_sh;
    const float omb = 1.f - bta;
    const float4* h4 = (const float4*)(h_t + (size_t)b * DIM);
    const float4* s4 = (const float4*)(s_t + (size_t)b * DIM);
    float4* o4 = (float4*)(out + (size_t)b * DIM);
    for (int d4 = tid; d4 < DIM / 4; d4 += 256) {
        const float4* vp = (const float4*)Vb + d4;
        float ax = 0.f, ay = 0.f, az = 0.f, aw = 0.f;
        #pragma unroll 7
        for (int l = 0; l < KR; ++l) {
            const float al = alpha_l[l];
            float4 v = vp[(size_t)l * (DIM / 4)];
            ax += al * v.x; ay += al * v.y; az += al * v.z; aw += al * v.w;
        }
        float4 hv = h4[d4], sv = s4[d4], o;
        o.x = bta * sv.x + omb * ax + hv.x;
        o.y = bta * sv.y + omb * ay + hv.y;
        o.z = bta * sv.z + omb * az + hv.z;
        o.w = bta * sv.w + omb * aw + hv.w;
        o4[d4] = o;
    }
}

extern "C" void kernel_launch(void* const* d_in, const int* in_sizes, int n_in,
                              void* d_out, int out_size, void* d_ws, size_t ws_size,
                              hipStream_t stream) {
    const float* V     = (const float*)d_in[0];
    const float* h_t   = (const float*)d_in[1];
    const float* s_t   = (const float*)d_in[2];
    const float* W_v   = (const float*)d_in[3];
    const float* W_g   = (const float*)d_in[4];
    const float* W_s   = (const float*)d_in[5];
    const float* w_h   = (const float*)d_in[6];
    const float* w_h_s = (const float*)d_in[7];
    float* out = (float*)d_out;

    // ws layout: Wgt [B*49 f32] | Ts [B*49 f32] | Wvb [49*2048 bf16]  (~3.4 MB)
    float* Wgt = (float*)d_ws;
    float* Ts  = Wgt + (size_t)BATCH * KR;
    unsigned short* Wvb = (unsigned short*)(Ts + (size_t)BATCH * KR);

    hipLaunchKernelGGL(precompute_kernel, dim3((BATCH * KR) / 256), dim3(256), 0, stream,
                       h_t, s_t, W_v, W_g, W_s, w_h_s, Wgt, Ts, Wvb);
    hipLaunchKernelGGL(fused_kernel, dim3(BATCH), dim3(256), 0, stream,
                       V, h_t, s_t, w_h, Wgt, Ts, Wvb, out);
}

// Round 2
// 1536.964 us; speedup vs baseline: 1.0284x; 1.0284x over previous
//
#include <hip/hip_runtime.h>
#include <hip/hip_bf16.h>

#define BATCH 2048
#define DIM   2048
#define KR    49     // K_REG (= L, number of V slots)
#define KC    64     // K-chunk of D per MFMA step

typedef __attribute__((ext_vector_type(8))) short short8;   // 8 bf16 = 4 VGPRs
typedef __attribute__((ext_vector_type(4))) float float4v;  // MFMA accumulator

__device__ __forceinline__ unsigned short f2b(float x) {
    __hip_bfloat16 h = __float2bfloat16(x);
    return __builtin_bit_cast(unsigned short, h);
}

// pack two fp32 -> two bf16 (truncate toward zero: keep high 16 bits)
__device__ __forceinline__ unsigned int pack2_trunc(float lo, float hi) {
    unsigned int a = __builtin_bit_cast(unsigned int, lo);
    unsigned int b = __builtin_bit_cast(unsigned int, hi);
    return (b & 0xffff0000u) | (a >> 16);
}

// Kernel 1: W_gt[b,k] = h_t[b]·W_g[k];  Ts[b,k] = tanh(s_t[b]·W_s[k] + W_gt)·w_h_s[k];
// plus fp32->bf16 (RNE) conversion of W_v.
__global__ __launch_bounds__(256) void precompute_kernel(
    const float* __restrict__ h_t, const float* __restrict__ s_t,
    const float* __restrict__ W_v, const float* __restrict__ W_g,
    const float* __restrict__ W_s, const float* __restrict__ w_h_s,
    float* __restrict__ Wgt, float* __restrict__ Ts,
    unsigned short* __restrict__ Wvb)
{
    const int idx = blockIdx.x * 256 + threadIdx.x;
    if (idx >= BATCH * KR) return;
    Wvb[idx] = f2b(W_v[idx]);          // exact 1:1 cover of 49*2048 elements
    const int b = idx / KR;
    const int k = idx - b * KR;
    const float4* h4 = (const float4*)(h_t + (size_t)b * DIM);
    const float4* s4 = (const float4*)(s_t + (size_t)b * DIM);
    const float4* g4 = (const float4*)(W_g + (size_t)k * DIM);
    const float4* w4 = (const float4*)(W_s + (size_t)k * DIM);
    float ag = 0.f, as = 0.f;
    #pragma unroll 4
    for (int d = 0; d < DIM / 4; ++d) {
        float4 hv = h4[d], gv = g4[d];
        ag += hv.x * gv.x + hv.y * gv.y + hv.z * gv.z + hv.w * gv.w;
        float4 sv = s4[d], wv = w4[d];
        as += sv.x * wv.x + sv.y * wv.y + sv.z * wv.z + sv.w * wv.w;
    }
    Wgt[idx] = ag;
    Ts[idx]  = tanhf(as + ag) * w_h_s[k];
}

// Kernel 2: one block per batch b. Pass 1: T = V[b](49x2048) · W_v^T via bf16 MFMA
// with fragments loaded DIRECTLY from global (no LDS, no barriers in the K-loop).
// z_l = sum_k tanh(T+Wgt)·w_h. Softmax over [z_0..z_48, sent]. Pass 2: out.
__global__ __launch_bounds__(256) void fused_kernel(
    const float* __restrict__ V, const float* __restrict__ h_t,
    const float* __restrict__ s_t, const float* __restrict__ w_h,
    const float* __restrict__ Wgt, const float* __restrict__ Ts,
    const unsigned short* __restrict__ Wvb, float* __restrict__ out)
{
    const int b    = blockIdx.x;
    const int tid  = threadIdx.x;
    const int wave = tid >> 6;
    const int lane = tid & 63;
    const int quad = lane >> 4;
    const int l16  = lane & 15;

    __shared__ float z_lds[64];
    __shared__ float alpha_l[KR];
    __shared__ float wgt_l[64];
    __shared__ float wh_l[64];
    __shared__ float beta_sh;

    if (tid < KR) {
        wgt_l[tid] = Wgt[(size_t)b * KR + tid];
        wh_l[tid]  = w_h[tid];
    } else if (tid < 64) {
        wgt_l[tid] = 0.f;
        wh_l[tid]  = 0.f;
    }
    __syncthreads();

    const float* Vb = V + (size_t)b * KR * DIM;

    // A row for this lane (MFMA A layout: m = l16), clamped into valid range;
    // rows 49..63 compute duplicates of row 48, discarded at the epilogue.
    const int arow = min(wave * 16 + l16, KR - 1);
    const float* aBase = Vb + (size_t)arow * DIM + quad * 8;

    // B rows for the 4 col-tiles (n = t*16 + l16), clamped.
    const unsigned short* bBase[4];
    #pragma unroll
    for (int t = 0; t < 4; ++t) {
        const int brow = min(t * 16 + l16, KR - 1);
        bBase[t] = Wvb + (size_t)brow * DIM + quad * 8;
    }

    float4v acc[4];
    #pragma unroll
    for (int t = 0; t < 4; ++t) acc[t] = (float4v){0.f, 0.f, 0.f, 0.f};

    #pragma unroll 2
    for (int kc = 0; kc < DIM; kc += KC) {
        #pragma unroll
        for (int s = 0; s < 2; ++s) {           // two k-steps of 32 per chunk
            const float* ap = aBase + kc + s * 32;
            float4 v0 = *(const float4*)ap;
            float4 v1 = *(const float4*)(ap + 4);
            uint4 p;
            p.x = pack2_trunc(v0.x, v0.y);
            p.y = pack2_trunc(v0.z, v0.w);
            p.z = pack2_trunc(v1.x, v1.y);
            p.w = pack2_trunc(v1.z, v1.w);
            short8 af = __builtin_bit_cast(short8, p);
            #pragma unroll
            for (int t = 0; t < 4; ++t) {
                short8 bf = *(const short8*)(bBase[t] + kc + s * 32);
                acc[t] = __builtin_amdgcn_mfma_f32_16x16x32_bf16(af, bf, acc[t], 0, 0, 0);
            }
        }
    }

    // z_l = sum_k tanh(T[l,k] + Wgt[k]) * w_h[k]
    // lane holds C[row = wave*16 + quad*4 + r][col = t*16 + l16]
    float zp[4] = {0.f, 0.f, 0.f, 0.f};
    #pragma unroll
    for (int t = 0; t < 4; ++t) {
        const int col = t * 16 + l16;
        const float wg = wgt_l[col];        // 0 for col >= KR
        const float wh = wh_l[col];         // 0 for col >= KR -> masks garbage
        #pragma unroll
        for (int r = 0; r < 4; ++r)
            zp[r] += tanhf(acc[t][r] + wg) * wh;
    }
    #pragma unroll
    for (int off = 1; off < 16; off <<= 1) {
        #pragma unroll
        for (int r = 0; r < 4; ++r)
            zp[r] += __shfl_xor(zp[r], off, 64);
    }
    if (l16 == 0) {
        #pragma unroll
        for (int r = 0; r < 4; ++r) {
            const int row = wave * 16 + quad * 4 + r;
            if (row < KR) z_lds[row] = zp[r];
        }
    }
    __syncthreads();

    // softmax over 50 logits in wave 0; sent = sum_k Ts[b,k]
    if (wave == 0) {
        float tv = (lane < KR) ? Ts[(size_t)b * KR + lane] : 0.f;
        float sent = tv;
        #pragma unroll
        for (int off = 1; off < 64; off <<= 1) sent += __shfl_xor(sent, off, 64);
        float x = (lane < KR) ? z_lds[lane] : ((lane == KR) ? sent : -1e30f);
        float m = x;
        #pragma unroll
        for (int off = 1; off < 64; off <<= 1) m = fmaxf(m, __shfl_xor(m, off, 64));
        float e = (lane <= KR) ? expf(x - m) : 0.f;
        float s = e;
        #pragma unroll
        for (int off = 1; off < 64; off <<= 1) s += __shfl_xor(s, off, 64);
        const float a = e / s;
        if (lane < KR) alpha_l[lane] = a;
        if (lane == KR) beta_sh = a;
    }
    __syncthreads();

    // pass 2: out[b,d] = beta*s_t + (1-beta)*sum_l alpha_l V[b,l,d] + h_t
    const float bta = beta_sh;
    const float omb = 1.f - bta;
    const float4* h4 = (const float4*)(h_t + (size_t)b * DIM);
    const float4* s4 = (const float4*)(s_t + (size_t)b * DIM);
    float4* o4 = (float4*)(out + (size_t)b * DIM);
    for (int d4 = tid; d4 < DIM / 4; d4 += 256) {
        const float4* vp = (const float4*)Vb + d4;
        float ax = 0.f, ay = 0.f, az = 0.f, aw = 0.f;
        #pragma unroll 7
        for (int l = 0; l < KR; ++l) {
            const float al = alpha_l[l];
            float4 v = vp[(size_t)l * (DIM / 4)];
            ax += al * v.x; ay += al * v.y; az += al * v.z; aw += al * v.w;
        }
        float4 hv = h4[d4], sv = s4[d4], o;
        o.x = bta * sv.x + omb * ax + hv.x;
        o.y = bta * sv.y + omb * ay + hv.y;
        o.z = bta * sv.z + omb * az + hv.z;
        o.w = bta * sv.w + omb * aw + hv.w;
        o4[d4] = o;
    }
}

extern "C" void kernel_launch(void* const* d_in, const int* in_sizes, int n_in,
                              void* d_out, int out_size, void* d_ws, size_t ws_size,
                              hipStream_t stream) {
    const float* V     = (const float*)d_in[0];
    const float* h_t   = (const float*)d_in[1];
    const float* s_t   = (const float*)d_in[2];
    const float* W_v   = (const float*)d_in[3];
    const float* W_g   = (const float*)d_in[4];
    const float* W_s   = (const float*)d_in[5];
    const float* w_h   = (const float*)d_in[6];
    const float* w_h_s = (const float*)d_in[7];
    float* out = (float*)d_out;

    // ws layout: Wgt [B*49 f32] | Ts [B*49 f32] | Wvb [49*2048 bf16]  (~1 MB)
    float* Wgt = (float*)d_ws;
    float* Ts  = Wgt + (size_t)BATCH * KR;
    unsigned short* Wvb = (unsigned short*)(Ts + (size_t)BATCH * KR);

    hipLaunchKernelGGL(precompute_kernel, dim3((BATCH * KR + 255) / 256), dim3(256), 0, stream,
                       h_t, s_t, W_v, W_g, W_s, w_h_s, Wgt, Ts, Wvb);
    hipLaunchKernelGGL(fused_kernel, dim3(BATCH), dim3(256), 0, stream,
                       V, h_t, s_t, w_h, Wgt, Ts, Wvb, out);
}